// Round 9
// baseline (91.027 us; speedup 1.0000x reference)
//
#include <hip/hip_runtime.h>
#include <hip/hip_bf16.h>
#include <math.h>

#define N_ROWS 8192
#define D_DIM  256
#define BM 128
#define BN 64
#define JSPLIT 16
#define JRANGE (N_ROWS / JSPLIT)     // 512
#define NT (JRANGE / BN)             // 8 j-steps per block

typedef __attribute__((ext_vector_type(4))) float f32x4;

// ------- kernel 1: L2-normalize rows, cast to fp8 e4m3 (+ zero accum) -------
__global__ void norm_cast_kernel(const float* __restrict__ out0,
                                 const float* __restrict__ out1,
                                 unsigned char* __restrict__ a_f8,
                                 unsigned char* __restrict__ b_f8,
                                 float* __restrict__ zero_me) {   // pos+all, 2*N floats
    int gtid = blockIdx.x * blockDim.x + threadIdx.x;
    if (gtid < 2 * N_ROWS) zero_me[gtid] = 0.0f;

    int wave = gtid >> 6;
    int lane = threadIdx.x & 63;
    const float* src    = (wave < N_ROWS) ? out0 : out1;
    unsigned char* dst  = (wave < N_ROWS) ? a_f8 : b_f8;
    int row = (wave < N_ROWS) ? wave : wave - N_ROWS;

    float4 v = *reinterpret_cast<const float4*>(src + (size_t)row * D_DIM + lane * 4);
    float ss = v.x * v.x + v.y * v.y + v.z * v.z + v.w * v.w;
    #pragma unroll
    for (int off = 32; off; off >>= 1) ss += __shfl_xor(ss, off);
    float inv = 1.0f / fmaxf(sqrtf(ss), 1e-12f);

    // pack 4 normalized floats -> 4 fp8 e4m3 bytes (OCP on gfx950)
    int packed = __builtin_amdgcn_cvt_pk_fp8_f32(v.x * inv, v.y * inv, 0, 0);
    packed     = __builtin_amdgcn_cvt_pk_fp8_f32(v.z * inv, v.w * inv, packed, 1);
    *reinterpret_cast<unsigned int*>(dst + (size_t)row * D_DIM + lane * 4) =
        (unsigned int)packed;
}

// ------- kernel 2: fp8 flash-style fused GEMM + exp + masked row-sums -------
// 1024 blocks = 64 row-tiles x 16 j-splits (jsplit = blockIdx&15). 4 waves
// (2 wr x 2 wc), wave-tile 64x32. A-slice per wave PINNED in regs (64 VGPR
// fp8). B double-buffered in LDS (2x16KB = 32KB -> 3+ blocks/CU at ~160 VGPR,
// 3 waves/SIMD). Staged via global_load_lds(16B), 16B-slot XOR swizzle:
//   LDS[row][slot16] = global[row][slot16 ^ (row&15)]  (16 slots per 256B row)
__global__ __launch_bounds__(256, 3)
void fused_flash_kernel(const unsigned char* __restrict__ A,
                        const unsigned char* __restrict__ B,
                        const int* __restrict__ labels,
                        float* __restrict__ pos_sum,
                        float* __restrict__ all_sum) {
    __shared__ unsigned char Bs[2][BN * D_DIM];   // 2 x 16 KB

    const int tid    = threadIdx.x;
    const int lane   = tid & 63;
    const int wid    = tid >> 6;        // 0..3
    const int wr     = wid >> 1;        // 0..1  (64-row band)
    const int wc     = wid & 1;         // 0..1  (32-col half)
    const int lane16 = lane & 15;
    const int kgrp   = lane >> 4;       // 0..3

    const int jsplit = blockIdx.x & 15;
    const int rowt   = blockIdx.x >> 4;
    const int i0     = rowt * BM;
    const int jbase  = jsplit * JRANGE;

    // ---- A fragments -> registers (once), PINNED ----
    // frag for (m, ks): row = wr*64+m*16+lane16, bytes [ks*32 + kgrp*8, +8)
    long af[4][8];
    #pragma unroll
    for (int m = 0; m < 4; ++m) {
        const unsigned char* ap =
            A + (size_t)(i0 + wr * 64 + m * 16 + lane16) * D_DIM + kgrp * 8;
        #pragma unroll
        for (int ks = 0; ks < 8; ++ks)
            af[m][ks] = *reinterpret_cast<const long*>(ap + ks * 32);
    }
    #pragma unroll
    for (int m = 0; m < 4; ++m)
        #pragma unroll
        for (int ks = 0; ks < 8; ++ks)
            asm volatile("" : "+v"(af[m][ks]));

    // row labels (0..99 fit in a byte), packed 4-per-int, pinned
    int labp[4];
    #pragma unroll
    for (int m = 0; m < 4; ++m) {
        int4 v = *reinterpret_cast<const int4*>(labels + i0 + wr * 64 + m * 16 + kgrp * 4);
        labp[m] = v.x | (v.y << 8) | (v.z << 16) | (v.w << 24);
        asm volatile("" : "+v"(labp[m]));
    }

    // ---- B staging: 16 chunks of 1KB (4 rows x 256B), 4 per wave ----
    // lane l -> row-in-chunk l>>4, slot16 (l&15); source pre-swizzled.
    auto stage = [&](int buf, int t) {
        const int jrow0 = jbase + t * BN;
        #pragma unroll
        for (int cc = 0; cc < 4; ++cc) {
            int c  = wid * 4 + cc;                  // chunk 0..15 (wave-uniform)
            int gr = jrow0 + c * 4 + (lane >> 4);   // global B row
            const unsigned char* src =
                B + (size_t)gr * D_DIM + (((lane & 15) ^ (gr & 15)) << 4);
            __builtin_amdgcn_global_load_lds(
                (const __attribute__((address_space(1))) void*)src,
                (__attribute__((address_space(3))) void*)(&Bs[buf][0] + c * 1024),
                16, 0, 0);
        }
    };

    float allp[4][4] = {};
    float posp[4][4] = {};

    stage(0, 0);
    __syncthreads();

    for (int t = 0; t < NT; ++t) {
        const int cur = t & 1;
        if (t + 1 < NT) stage(cur ^ 1, t + 1);

        // column labels early (hide under MFMA)
        const int jc    = jbase + t * BN + wc * 32 + lane16;
        const int labc0 = labels[jc];
        const int labc1 = labels[jc + 16];

        // ---- compute 128x64 logits tile: 64 MFMA per wave ----
        f32x4 acc[4][2] = {};
        __builtin_amdgcn_s_setprio(1);
        #pragma unroll
        for (int ks = 0; ks < 8; ++ks) {
            long bv[2];
            #pragma unroll
            for (int n = 0; n < 2; ++n) {
                int tr = wc * 32 + n * 16 + lane16;           // tile row (B col)
                int s16 = (ks * 2 + (kgrp >> 1)) ^ (tr & 15); // swizzled 16B slot
                bv[n] = *reinterpret_cast<const long*>(
                    &Bs[cur][0] + tr * 256 + (s16 << 4) + ((kgrp & 1) << 3));
            }
            #pragma unroll
            for (int m = 0; m < 4; ++m)
                #pragma unroll
                for (int n = 0; n < 2; ++n)
                    acc[m][n] = __builtin_amdgcn_mfma_f32_16x16x32_fp8_fp8(
                        af[m][ks], bv[n], acc[m][n], 0, 0, 0);
        }
        __builtin_amdgcn_s_setprio(0);

        __syncthreads();   // all reads of Bs[cur] done; stage(t+1) drained

        // ---- epilogue: exp + mask, accumulate row sums in registers ----
        #pragma unroll
        for (int m = 0; m < 4; ++m) {
            #pragma unroll
            for (int r = 0; r < 4; ++r) {
                float e0 = __expf(acc[m][0][r] * 2.0f);   // / TEMPERATURE
                float e1 = __expf(acc[m][1][r] * 2.0f);
                allp[m][r] += e0 + e1;
                int lr = (labp[m] >> (r * 8)) & 0xFF;
                posp[m][r] += (lr == labc0 ? e0 : 0.0f) + (lr == labc1 ? e1 : 0.0f);
            }
        }
    }

    // ---- final: reduce across the 16 col-lanes, one atomic per row ----
    #pragma unroll
    for (int m = 0; m < 4; ++m) {
        #pragma unroll
        for (int r = 0; r < 4; ++r) {
            float a = allp[m][r], p = posp[m][r];
            #pragma unroll
            for (int off = 1; off < 16; off <<= 1) {
                a += __shfl_xor(a, off);
                p += __shfl_xor(p, off);
            }
            if (lane16 == 0) {
                int grow = i0 + wr * 64 + m * 16 + kgrp * 4 + r;
                atomicAdd(&all_sum[grow], a);
                atomicAdd(&pos_sum[grow], p);
            }
        }
    }
}

// ---------------- kernel 3: final loss reduction ----------------------------
__global__ void loss_kernel(const float* __restrict__ pos_sum,
                            const float* __restrict__ all_sum,
                            float* __restrict__ out) {
    float acc = 0.0f;
    for (int i = threadIdx.x; i < N_ROWS; i += 1024)
        acc += logf(pos_sum[i] / all_sum[i]);
    #pragma unroll
    for (int off = 32; off; off >>= 1) acc += __shfl_xor(acc, off);
    __shared__ float red[16];
    int wv = threadIdx.x >> 6, lane = threadIdx.x & 63;
    if (lane == 0) red[wv] = acc;
    __syncthreads();
    if (threadIdx.x < 64) {
        float s = (threadIdx.x < 16) ? red[threadIdx.x] : 0.0f;
        #pragma unroll
        for (int off = 8; off; off >>= 1) s += __shfl_xor(s, off);
        if (threadIdx.x == 0) out[0] = -s / (float)N_ROWS;
    }
}

// ---------------- launch -----------------------------------------------------
extern "C" void kernel_launch(void* const* d_in, const int* in_sizes, int n_in,
                              void* d_out, int out_size, void* d_ws, size_t ws_size,
                              hipStream_t stream) {
    const float* out0   = (const float*)d_in[0];
    const float* out1   = (const float*)d_in[1];
    const int*   labels = (const int*)d_in[2];
    float*       out    = (float*)d_out;

    unsigned char* a_f8 = (unsigned char*)d_ws;
    unsigned char* b_f8 = a_f8 + (size_t)N_ROWS * D_DIM;
    float* pos  = (float*)(b_f8 + (size_t)N_ROWS * D_DIM);
    float* alls = pos + N_ROWS;

    norm_cast_kernel<<<2 * N_ROWS / 4, 256, 0, stream>>>(out0, out1, a_f8, b_f8, pos);

    fused_flash_kernel<<<JSPLIT * (N_ROWS / BM), 256, 0, stream>>>(a_f8, b_f8, labels, pos, alls);

    loss_kernel<<<1, 1024, 0, stream>>>(pos, alls, out);
}